// Round 6
// baseline (237.501 us; speedup 1.0000x reference)
//
#include <hip/hip_runtime.h>

typedef unsigned int uint;
typedef unsigned short ushort;

#define IN_C 128
#define HID  32

// ---- bf16 helpers (fp32 accumulate everywhere; RNE on store) --------------
__device__ __forceinline__ float bf_lo(uint u) { return __uint_as_float(u << 16); }
__device__ __forceinline__ float bf_hi(uint u) { return __uint_as_float(u & 0xffff0000u); }
__device__ __forceinline__ uint  f2bf(float f) {
    uint u = __float_as_uint(f);
    return (u + 0x7fffu + ((u >> 16) & 1u)) >> 16;   // RNE; inputs are finite
}

// ---------------------------------------------------------------------------
// K1: fused prep: blocks [0,nbE) compute r0 = relu(x @ w_embed) -> bf16;
// blocks [nbE,..) build both CSR indptrs by binary search.
// ---------------------------------------------------------------------------
__global__ void prep_kernel(const float* __restrict__ x,
                            const float* __restrict__ w,
                            ushort* __restrict__ r0,
                            const int* __restrict__ a1r, int E1, int* __restrict__ ip1,
                            const int* __restrict__ a2r, int E2, int* __restrict__ ip2,
                            int n, int nbE) {
    __shared__ float wl[IN_C * HID];
    const int tid = threadIdx.x;
    if (blockIdx.x < nbE) {
        for (int i = tid; i < IN_C * HID; i += blockDim.x) wl[i] = w[i];
        __syncthreads();
        const int row = blockIdx.x * 16 + tid / 16;
        const int h0  = (tid % 16) * 2;
        if (row >= n) return;
        const float4* xr = (const float4*)(x + (size_t)row * IN_C);
        float a0 = 0.f, a1 = 0.f;
#pragma unroll
        for (int k4 = 0; k4 < IN_C / 4; ++k4) {
            float4 xv = xr[k4];
            a0 += xv.x * wl[(4*k4+0)*HID + h0];  a1 += xv.x * wl[(4*k4+0)*HID + h0+1];
            a0 += xv.y * wl[(4*k4+1)*HID + h0];  a1 += xv.y * wl[(4*k4+1)*HID + h0+1];
            a0 += xv.z * wl[(4*k4+2)*HID + h0];  a1 += xv.z * wl[(4*k4+2)*HID + h0+1];
            a0 += xv.w * wl[(4*k4+3)*HID + h0];  a1 += xv.w * wl[(4*k4+3)*HID + h0+1];
        }
        uint p = f2bf(fmaxf(a0, 0.f)) | (f2bf(fmaxf(a1, 0.f)) << 16);
        ((uint*)r0)[(size_t)row * 16 + (tid % 16)] = p;
    } else {
        const int i = (blockIdx.x - nbE) * 256 + tid;
        if (i > n) return;
        int lo = 0, hi = E1;
        while (lo < hi) { int m = (lo + hi) >> 1; if (a1r[m] < i) lo = m + 1; else hi = m; }
        ip1[i] = lo;
        lo = 0; hi = E2;
        while (lo < hi) { int m = (lo + hi) >> 1; if (a2r[m] < i) lo = m + 1; else hi = m; }
        ip2[i] = lo;
    }
}

// ---------------------------------------------------------------------------
// K2: fused-level SpMM + ReLU, bf16 features / fp32 accumulate.
// ROWS rows per wave; per row: L = C/8 feature-lanes (uint4 = 8 bf16 feats)
// x W edge-ways. Inner batch = 8 edges/way: 2 int4 + 2 float4 + 8 gathers all
// issued before any consume (~10 loads in flight/wave). Then a 4-edge mid
// loop and scalar tail. No cross-iteration register rotation (R5 regressed).
// Blocks [0,nb2) = A2 (heavy, out col off C); rest = A1 (off 0).
// ---------------------------------------------------------------------------
template <int C, int ROWS>
__global__ __launch_bounds__(256) void spmm_level(
        const int* __restrict__ ip1, const int* __restrict__ col1,
        const float* __restrict__ val1,
        const int* __restrict__ ip2, const int* __restrict__ col2,
        const float* __restrict__ val2,
        const ushort* __restrict__ xin, ushort* __restrict__ out,
        int n, int nb2) {
    constexpr int L    = C / 8;        // feature lanes per row
    constexpr int SUBL = 64 / ROWS;    // lanes per row
    constexpr int W    = SUBL / L;     // edge ways per row
    const int lane = threadIdx.x & 63;
    const int wave = threadIdx.x >> 6;
    const int sub  = lane / SUBL;
    const int li   = lane % SUBL;
    const int fl   = li % L;
    const int way  = li / L;

    int bid = blockIdx.x;
    const int* ip; const int* col; const float* val; int off;
    if (bid < nb2) {             ip = ip2; col = col2; val = val2; off = C; }
    else           { bid -= nb2; ip = ip1; col = col1; val = val1; off = 0; }

    const int row = (bid * 4 + wave) * ROWS + sub;
    if (row >= n) return;

    const ushort* xbase = xin + fl * 8;
    float acc[8];
#pragma unroll
    for (int j = 0; j < 8; ++j) acc[j] = 0.f;

    auto gat = [&](int c) -> uint4 {
        return *(const uint4*)(xbase + (size_t)c * C);
    };
    auto fmadd = [&](const uint4& u, float v) {
        acc[0] += v * bf_lo(u.x); acc[1] += v * bf_hi(u.x);
        acc[2] += v * bf_lo(u.y); acc[3] += v * bf_hi(u.y);
        acc[4] += v * bf_lo(u.z); acc[5] += v * bf_hi(u.z);
        acc[6] += v * bf_lo(u.w); acc[7] += v * bf_hi(u.w);
    };

    const int s = ip[row];
    const int e = ip[row + 1];
    int sv = (s + 3) & ~3; if (sv > e) sv = e;     // 16B-align vector loads
    // unaligned head (<=3 edges)
    for (int idx = s + way; idx < sv; idx += W) fmadd(gat(col[idx]), val[idx]);

    const int*   cb = col + sv;
    const float* vb = val + sv;
    // main: 8 edges per way per iteration
    const int nv8 = (e - sv) / (8 * W);
    for (int i = 0; i < nv8; ++i) {
        const int base = (i * W + way) * 8;
        const int4   c0 = *(const int4*)  (cb + base);
        const int4   c1 = *(const int4*)  (cb + base + 4);
        const float4 v0 = *(const float4*)(vb + base);
        const float4 v1 = *(const float4*)(vb + base + 4);
        const uint4 g0 = gat(c0.x), g1 = gat(c0.y), g2 = gat(c0.z), g3 = gat(c0.w);
        const uint4 g4 = gat(c1.x), g5 = gat(c1.y), g6 = gat(c1.z), g7 = gat(c1.w);
        fmadd(g0, v0.x); fmadd(g1, v0.y); fmadd(g2, v0.z); fmadd(g3, v0.w);
        fmadd(g4, v1.x); fmadd(g5, v1.y); fmadd(g6, v1.z); fmadd(g7, v1.w);
    }
    int done = sv + nv8 * 8 * W;
    // mid: 4 edges per way
    const int nv4 = (e - done) / (4 * W);
    if (nv4 > 0) {
        const int base = (done - sv) + way * 4;
        const int4   c0 = *(const int4*)  (cb + base);
        const float4 v0 = *(const float4*)(vb + base);
        const uint4 g0 = gat(c0.x), g1 = gat(c0.y), g2 = gat(c0.z), g3 = gat(c0.w);
        fmadd(g0, v0.x); fmadd(g1, v0.y); fmadd(g2, v0.z); fmadd(g3, v0.w);
        done += 4 * W;
    }
    // scalar tail
    for (int idx = done + way; idx < e; idx += W) fmadd(gat(col[idx]), val[idx]);

    // cross-way in-register reduction (stays within each row's subgroup)
#pragma unroll
    for (int m = L; m < SUBL; m <<= 1)
#pragma unroll
        for (int j = 0; j < 8; ++j) acc[j] += __shfl_xor(acc[j], m, 64);

    if (way == 0) {
        uint4 p;
        p.x = f2bf(fmaxf(acc[0],0.f)) | (f2bf(fmaxf(acc[1],0.f)) << 16);
        p.y = f2bf(fmaxf(acc[2],0.f)) | (f2bf(fmaxf(acc[3],0.f)) << 16);
        p.z = f2bf(fmaxf(acc[4],0.f)) | (f2bf(fmaxf(acc[5],0.f)) << 16);
        p.w = f2bf(fmaxf(acc[6],0.f)) | (f2bf(fmaxf(acc[7],0.f)) << 16);
        *(uint4*)(out + (size_t)row * (2 * C) + off + fl * 8) = p;
    }
}

// ---------------------------------------------------------------------------
// K3: out = [r0 | r1 | r2] @ w_classify  (bf16 features, fp32 weights in LDS)
// ---------------------------------------------------------------------------
#define CDIM 224
#define OUT_C 16
__global__ void classify_kernel(const ushort* __restrict__ r0,
                                const ushort* __restrict__ r1,
                                const ushort* __restrict__ r2,
                                const float* __restrict__ w,
                                float* __restrict__ out, int n) {
    __shared__ float wl[CDIM * OUT_C];
    const int tid = threadIdx.x;
    for (int i = tid; i < CDIM * OUT_C; i += blockDim.x) wl[i] = w[i];
    __syncthreads();
    const int row = blockIdx.x * 16 + tid / 16;
    const int o   = tid % 16;
    if (row >= n) return;
    float acc = 0.f;

    const uint4* a = (const uint4*)(r0 + (size_t)row * 32);
#pragma unroll
    for (int q = 0; q < 4; ++q) {
        uint4 u = a[q]; int j = q * 8;
        acc += bf_lo(u.x) * wl[(j+0)*OUT_C + o];  acc += bf_hi(u.x) * wl[(j+1)*OUT_C + o];
        acc += bf_lo(u.y) * wl[(j+2)*OUT_C + o];  acc += bf_hi(u.y) * wl[(j+3)*OUT_C + o];
        acc += bf_lo(u.z) * wl[(j+4)*OUT_C + o];  acc += bf_hi(u.z) * wl[(j+5)*OUT_C + o];
        acc += bf_lo(u.w) * wl[(j+6)*OUT_C + o];  acc += bf_hi(u.w) * wl[(j+7)*OUT_C + o];
    }
    const uint4* b = (const uint4*)(r1 + (size_t)row * 64);
#pragma unroll
    for (int q = 0; q < 8; ++q) {
        uint4 u = b[q]; int j = 32 + q * 8;
        acc += bf_lo(u.x) * wl[(j+0)*OUT_C + o];  acc += bf_hi(u.x) * wl[(j+1)*OUT_C + o];
        acc += bf_lo(u.y) * wl[(j+2)*OUT_C + o];  acc += bf_hi(u.y) * wl[(j+3)*OUT_C + o];
        acc += bf_lo(u.z) * wl[(j+4)*OUT_C + o];  acc += bf_hi(u.z) * wl[(j+5)*OUT_C + o];
        acc += bf_lo(u.w) * wl[(j+6)*OUT_C + o];  acc += bf_hi(u.w) * wl[(j+7)*OUT_C + o];
    }
    const uint4* c = (const uint4*)(r2 + (size_t)row * 128);
#pragma unroll
    for (int q = 0; q < 16; ++q) {
        uint4 u = c[q]; int j = 96 + q * 8;
        acc += bf_lo(u.x) * wl[(j+0)*OUT_C + o];  acc += bf_hi(u.x) * wl[(j+1)*OUT_C + o];
        acc += bf_lo(u.y) * wl[(j+2)*OUT_C + o];  acc += bf_hi(u.y) * wl[(j+3)*OUT_C + o];
        acc += bf_lo(u.z) * wl[(j+4)*OUT_C + o];  acc += bf_hi(u.z) * wl[(j+5)*OUT_C + o];
        acc += bf_lo(u.w) * wl[(j+6)*OUT_C + o];  acc += bf_hi(u.w) * wl[(j+7)*OUT_C + o];
    }
    out[(size_t)row * OUT_C + o] = acc;
}

// ---------------------------------------------------------------------------
extern "C" void kernel_launch(void* const* d_in, const int* in_sizes, int n_in,
                              void* d_out, int out_size, void* d_ws, size_t ws_size,
                              hipStream_t stream) {
    const float* x   = (const float*)d_in[0];
    const float* we  = (const float*)d_in[1];
    const float* wc  = (const float*)d_in[2];
    const int*   a1r = (const int*)  d_in[3];
    const int*   a1c = (const int*)  d_in[4];
    const float* a1v = (const float*)d_in[5];
    const int*   a2r = (const int*)  d_in[6];
    const int*   a2c = (const int*)  d_in[7];
    const float* a2v = (const float*)d_in[8];
    float* out = (float*)d_out;

    const int E1 = in_sizes[3];
    const int E2 = in_sizes[6];
    const int n  = in_sizes[0] / IN_C;   // 20000

    // Workspace (bf16 features): r0[n*32] r1[n*64] r2[n*128], then ip1/ip2
    ushort* r0 = (ushort*)d_ws;
    ushort* r1 = r0 + (size_t)n * 32;
    ushort* r2 = r1 + (size_t)n * 64;
    int*   ip1 = (int*)(r2 + (size_t)n * 128);
    int*   ip2 = ip1 + (n + 1);

    // 1) fused embed + indptr
    {
        const int nbE = (n + 15) / 16;
        const int nbI = (n + 1 + 255) / 256;
        prep_kernel<<<nbE + nbI, 256, 0, stream>>>(x, we, r0, a1r, E1, ip1,
                                                   a2r, E2, ip2, n, nbE);
    }

    // 2) level 1: r1 = relu([A1 r0 | A2 r0]); C=32, 2 rows/wave -> 8 rows/block
    {
        const int nb = (n + 7) / 8;
        spmm_level<32, 2><<<2 * nb, 256, 0, stream>>>(ip1, a1c, a1v, ip2, a2c, a2v,
                                                      r0, r1, n, nb);
    }
    // 3) level 2: r2 = relu([A1 r1 | A2 r1]); C=64, 1 row/wave -> 4 rows/block
    {
        const int nb = (n + 3) / 4;
        spmm_level<64, 1><<<2 * nb, 256, 0, stream>>>(ip1, a1c, a1v, ip2, a2c, a2v,
                                                      r1, r2, n, nb);
    }

    // 4) fused concat + classify
    classify_kernel<<<(n + 15) / 16, 256, 0, stream>>>(r0, r1, r2, wc, out, n);
}

// Round 7
// 217.642 us; speedup vs baseline: 1.0912x; 1.0912x over previous
//
#include <hip/hip_runtime.h>

typedef unsigned int uint;
typedef unsigned short ushort;

#define IN_C 128
#define HID  32

// ---- bf16 helpers (fp32 accumulate everywhere; RNE on store) --------------
__device__ __forceinline__ float bf_lo(uint u) { return __uint_as_float(u << 16); }
__device__ __forceinline__ float bf_hi(uint u) { return __uint_as_float(u & 0xffff0000u); }
__device__ __forceinline__ uint  f2bf(float f) {
    uint u = __float_as_uint(f);
    return (u + 0x7fffu + ((u >> 16) & 1u)) >> 16;   // RNE; inputs are finite
}

// ---------------------------------------------------------------------------
// K1: fused prep.
//   blocks [0,nbE)            : r0 = relu(x @ w_embed) -> bf16
//   blocks [nbE,nbE+nbI)      : both CSR indptrs by binary search
//   blocks [nbE+nbI, +nbT)    : warm-touch A2 col/val into LLC (overlaps the
//                               latency-bound searches; lvl-1 then reads warm)
// ---------------------------------------------------------------------------
__global__ void prep_kernel(const float* __restrict__ x,
                            const float* __restrict__ w,
                            ushort* __restrict__ r0,
                            const int* __restrict__ a1r, int E1, int* __restrict__ ip1,
                            const int* __restrict__ a2r, int E2, int* __restrict__ ip2,
                            const int* __restrict__ a2c, const float* __restrict__ a2v,
                            float* __restrict__ dummy,
                            int n, int nbE, int nbI, int nbT) {
    __shared__ float wl[IN_C * HID];
    const int tid = threadIdx.x;
    if (blockIdx.x < nbE) {
        for (int i = tid; i < IN_C * HID; i += blockDim.x) wl[i] = w[i];
        __syncthreads();
        const int row = blockIdx.x * 16 + tid / 16;
        const int h0  = (tid % 16) * 2;
        if (row >= n) return;
        const float4* xr = (const float4*)(x + (size_t)row * IN_C);
        float a0 = 0.f, a1 = 0.f;
#pragma unroll
        for (int k4 = 0; k4 < IN_C / 4; ++k4) {
            float4 xv = xr[k4];
            a0 += xv.x * wl[(4*k4+0)*HID + h0];  a1 += xv.x * wl[(4*k4+0)*HID + h0+1];
            a0 += xv.y * wl[(4*k4+1)*HID + h0];  a1 += xv.y * wl[(4*k4+1)*HID + h0+1];
            a0 += xv.z * wl[(4*k4+2)*HID + h0];  a1 += xv.z * wl[(4*k4+2)*HID + h0+1];
            a0 += xv.w * wl[(4*k4+3)*HID + h0];  a1 += xv.w * wl[(4*k4+3)*HID + h0+1];
        }
        uint p = f2bf(fmaxf(a0, 0.f)) | (f2bf(fmaxf(a1, 0.f)) << 16);
        ((uint*)r0)[(size_t)row * 16 + (tid % 16)] = p;
    } else if (blockIdx.x < nbE + nbI) {
        const int i = (blockIdx.x - nbE) * 256 + tid;
        if (i > n) return;
        int lo = 0, hi = E1;
        while (lo < hi) { int m = (lo + hi) >> 1; if (a1r[m] < i) lo = m + 1; else hi = m; }
        ip1[i] = lo;
        lo = 0; hi = E2;
        while (lo < hi) { int m = (lo + hi) >> 1; if (a2r[m] < i) lo = m + 1; else hi = m; }
        ip2[i] = lo;
    } else {
        // warm-touch A2 edge arrays (coalesced stream; result dummy-used)
        const int t = (blockIdx.x - nbE - nbI) * 256 + tid;
        const int stride = nbT * 256;
        const int total4 = E2 / 4;
        const float4* c4 = (const float4*)a2c;
        const float4* v4 = (const float4*)a2v;
        float s = 0.f;
        for (int i = t; i < total4; i += stride) {
            float4 u = c4[i], v = v4[i];
            s += u.x + u.y + u.z + u.w + v.x + v.y + v.z + v.w;
        }
        if (s == 123.456f) dummy[0] = s;   // never true in practice; defeats DCE
    }
}

// ---------------------------------------------------------------------------
// K2: fused-level SpMM + ReLU, bf16 features / fp32 accumulate.
// ROWS rows per wave; per row: L = C/8 feature-lanes (uint4 = 8 bf16 feats)
// x W edge-ways, 4-edge int4/float4 batches (R4 structure: VGPR ~36, max
// occupancy — TLP beats per-wave ILP here; R5/R6 widening regressed).
// Blocks [0,nb2) = A2 (heavy, out col off C); rest = A1 (off 0).
// ---------------------------------------------------------------------------
template <int C, int ROWS>
__global__ __launch_bounds__(256) void spmm_level(
        const int* __restrict__ ip1, const int* __restrict__ col1,
        const float* __restrict__ val1,
        const int* __restrict__ ip2, const int* __restrict__ col2,
        const float* __restrict__ val2,
        const ushort* __restrict__ xin, ushort* __restrict__ out,
        int n, int nb2) {
    constexpr int L    = C / 8;        // feature lanes per row
    constexpr int SUBL = 64 / ROWS;    // lanes per row
    constexpr int W    = SUBL / L;     // edge ways per row
    const int lane = threadIdx.x & 63;
    const int wave = threadIdx.x >> 6;
    const int sub  = lane / SUBL;
    const int li   = lane % SUBL;
    const int fl   = li % L;
    const int way  = li / L;

    int bid = blockIdx.x;
    const int* ip; const int* col; const float* val; int off;
    if (bid < nb2) {             ip = ip2; col = col2; val = val2; off = C; }
    else           { bid -= nb2; ip = ip1; col = col1; val = val1; off = 0; }

    const int row = (bid * 4 + wave) * ROWS + sub;
    if (row >= n) return;

    const ushort* xbase = xin + fl * 8;
    float acc[8];
#pragma unroll
    for (int j = 0; j < 8; ++j) acc[j] = 0.f;

    auto gat = [&](int c) -> uint4 {
        return *(const uint4*)(xbase + (size_t)c * C);
    };
    auto fmadd = [&](const uint4& u, float v) {
        acc[0] += v * bf_lo(u.x); acc[1] += v * bf_hi(u.x);
        acc[2] += v * bf_lo(u.y); acc[3] += v * bf_hi(u.y);
        acc[4] += v * bf_lo(u.z); acc[5] += v * bf_hi(u.z);
        acc[6] += v * bf_lo(u.w); acc[7] += v * bf_hi(u.w);
    };

    const int s = ip[row];
    const int e = ip[row + 1];
    int sv = (s + 3) & ~3; if (sv > e) sv = e;     // 16B-align vector loads
    const int nv = (e - sv) / (4 * W);

    // unaligned head (<=3 edges)
    for (int idx = s + way; idx < sv; idx += W) fmadd(gat(col[idx]), val[idx]);

    // vector body: 4 edges per way per iteration
    const int*   cb = col + sv;
    const float* vb = val + sv;
    for (int i = 0; i < nv; ++i) {
        const int base = (i * W + way) * 4;
        const int4   cc = *(const int4*)  (cb + base);
        const float4 vv = *(const float4*)(vb + base);
        const uint4 g0 = gat(cc.x), g1 = gat(cc.y), g2 = gat(cc.z), g3 = gat(cc.w);
        fmadd(g0, vv.x); fmadd(g1, vv.y); fmadd(g2, vv.z); fmadd(g3, vv.w);
    }
    // scalar tail
    for (int idx = sv + nv * 4 * W + way; idx < e; idx += W)
        fmadd(gat(col[idx]), val[idx]);

    // cross-way in-register reduction (stays within each row's subgroup)
#pragma unroll
    for (int m = L; m < SUBL; m <<= 1)
#pragma unroll
        for (int j = 0; j < 8; ++j) acc[j] += __shfl_xor(acc[j], m, 64);

    if (way == 0) {
        uint4 p;
        p.x = f2bf(fmaxf(acc[0],0.f)) | (f2bf(fmaxf(acc[1],0.f)) << 16);
        p.y = f2bf(fmaxf(acc[2],0.f)) | (f2bf(fmaxf(acc[3],0.f)) << 16);
        p.z = f2bf(fmaxf(acc[4],0.f)) | (f2bf(fmaxf(acc[5],0.f)) << 16);
        p.w = f2bf(fmaxf(acc[6],0.f)) | (f2bf(fmaxf(acc[7],0.f)) << 16);
        *(uint4*)(out + (size_t)row * (2 * C) + off + fl * 8) = p;
    }
}

// ---------------------------------------------------------------------------
// K3: out = [r0 | r1 | r2] @ w_classify  (bf16 features, fp32 weights in LDS)
// ---------------------------------------------------------------------------
#define CDIM 224
#define OUT_C 16
__global__ void classify_kernel(const ushort* __restrict__ r0,
                                const ushort* __restrict__ r1,
                                const ushort* __restrict__ r2,
                                const float* __restrict__ w,
                                float* __restrict__ out, int n) {
    __shared__ float wl[CDIM * OUT_C];
    const int tid = threadIdx.x;
    for (int i = tid; i < CDIM * OUT_C; i += blockDim.x) wl[i] = w[i];
    __syncthreads();
    const int row = blockIdx.x * 16 + tid / 16;
    const int o   = tid % 16;
    if (row >= n) return;
    float acc = 0.f;

    const uint4* a = (const uint4*)(r0 + (size_t)row * 32);
#pragma unroll
    for (int q = 0; q < 4; ++q) {
        uint4 u = a[q]; int j = q * 8;
        acc += bf_lo(u.x) * wl[(j+0)*OUT_C + o];  acc += bf_hi(u.x) * wl[(j+1)*OUT_C + o];
        acc += bf_lo(u.y) * wl[(j+2)*OUT_C + o];  acc += bf_hi(u.y) * wl[(j+3)*OUT_C + o];
        acc += bf_lo(u.z) * wl[(j+4)*OUT_C + o];  acc += bf_hi(u.z) * wl[(j+5)*OUT_C + o];
        acc += bf_lo(u.w) * wl[(j+6)*OUT_C + o];  acc += bf_hi(u.w) * wl[(j+7)*OUT_C + o];
    }
    const uint4* b = (const uint4*)(r1 + (size_t)row * 64);
#pragma unroll
    for (int q = 0; q < 8; ++q) {
        uint4 u = b[q]; int j = 32 + q * 8;
        acc += bf_lo(u.x) * wl[(j+0)*OUT_C + o];  acc += bf_hi(u.x) * wl[(j+1)*OUT_C + o];
        acc += bf_lo(u.y) * wl[(j+2)*OUT_C + o];  acc += bf_hi(u.y) * wl[(j+3)*OUT_C + o];
        acc += bf_lo(u.z) * wl[(j+4)*OUT_C + o];  acc += bf_hi(u.z) * wl[(j+5)*OUT_C + o];
        acc += bf_lo(u.w) * wl[(j+6)*OUT_C + o];  acc += bf_hi(u.w) * wl[(j+7)*OUT_C + o];
    }
    const uint4* c = (const uint4*)(r2 + (size_t)row * 128);
#pragma unroll
    for (int q = 0; q < 16; ++q) {
        uint4 u = c[q]; int j = 96 + q * 8;
        acc += bf_lo(u.x) * wl[(j+0)*OUT_C + o];  acc += bf_hi(u.x) * wl[(j+1)*OUT_C + o];
        acc += bf_lo(u.y) * wl[(j+2)*OUT_C + o];  acc += bf_hi(u.y) * wl[(j+3)*OUT_C + o];
        acc += bf_lo(u.z) * wl[(j+4)*OUT_C + o];  acc += bf_hi(u.z) * wl[(j+5)*OUT_C + o];
        acc += bf_lo(u.w) * wl[(j+6)*OUT_C + o];  acc += bf_hi(u.w) * wl[(j+7)*OUT_C + o];
    }
    out[(size_t)row * OUT_C + o] = acc;
}

// ---------------------------------------------------------------------------
extern "C" void kernel_launch(void* const* d_in, const int* in_sizes, int n_in,
                              void* d_out, int out_size, void* d_ws, size_t ws_size,
                              hipStream_t stream) {
    const float* x   = (const float*)d_in[0];
    const float* we  = (const float*)d_in[1];
    const float* wc  = (const float*)d_in[2];
    const int*   a1r = (const int*)  d_in[3];
    const int*   a1c = (const int*)  d_in[4];
    const float* a1v = (const float*)d_in[5];
    const int*   a2r = (const int*)  d_in[6];
    const int*   a2c = (const int*)  d_in[7];
    const float* a2v = (const float*)d_in[8];
    float* out = (float*)d_out;

    const int E1 = in_sizes[3];
    const int E2 = in_sizes[6];
    const int n  = in_sizes[0] / IN_C;   // 20000

    // Workspace (bf16 features): r0[n*32] r1[n*64] r2[n*128], ip1/ip2, dummy
    ushort* r0 = (ushort*)d_ws;
    ushort* r1 = r0 + (size_t)n * 32;
    ushort* r2 = r1 + (size_t)n * 64;
    int*   ip1 = (int*)(r2 + (size_t)n * 128);
    int*   ip2 = ip1 + (n + 1);
    float* dummy = (float*)(ip2 + (n + 2));

    // 1) fused embed + indptr + A2 edge-list warm-touch
    {
        const int nbE = (n + 15) / 16;
        const int nbI = (n + 1 + 255) / 256;
        const int nbT = 512;
        prep_kernel<<<nbE + nbI + nbT, 256, 0, stream>>>(
            x, we, r0, a1r, E1, ip1, a2r, E2, ip2, a2c, a2v, dummy,
            n, nbE, nbI, nbT);
    }

    // 2) level 1: r1 = relu([A1 r0 | A2 r0]); C=32, ROWS=2 -> W=8, 8 rows/block
    {
        const int nb = (n + 7) / 8;
        spmm_level<32, 2><<<2 * nb, 256, 0, stream>>>(ip1, a1c, a1v, ip2, a2c, a2v,
                                                      r0, r1, n, nb);
    }
    // 3) level 2: r2 = relu([A1 r1 | A2 r1]); C=64, ROWS=1 -> W=8, 4 rows/block
    {
        const int nb = (n + 3) / 4;
        spmm_level<64, 1><<<2 * nb, 256, 0, stream>>>(ip1, a1c, a1v, ip2, a2c, a2v,
                                                      r1, r2, n, nb);
    }

    // 4) fused concat + classify
    classify_kernel<<<(n + 15) / 16, 256, 0, stream>>>(r0, r1, r2, wc, out, n);
}